// Round 2
// baseline (940.317 us; speedup 1.0000x reference)
//
#include <hip/hip_runtime.h>
#include <hip/hip_bf16.h>

#define NN 100000
#define EE 1200000
#define HH 64
#define CC 10
#define GG 1000

// ---------- dtype-flexible load/store (bf=1: bf16, bf=0: fp32) ----------

__device__ __forceinline__ float ldin(const void* p, int i, int bf) {
    if (bf) {
        unsigned int w = ((unsigned int)((const unsigned short*)p)[i]) << 16;
        float f; __builtin_memcpy(&f, &w, 4); return f;
    }
    return ((const float*)p)[i];
}

__device__ __forceinline__ void stout(void* p, int i, float v, int bf) {
    if (bf) {
        unsigned int w; __builtin_memcpy(&w, &v, 4);
        unsigned int lsb = (w >> 16) & 1u;
        w += 0x7FFFu + lsb;                       // round-to-nearest-even
        ((unsigned short*)p)[i] = (unsigned short)(w >> 16);
    } else {
        ((float*)p)[i] = v;
    }
}

// Detect input float dtype. If x is bf16[], the LOW 16 bits of each 32-bit
// word are a bf16 N(0,1) sample (exponent in narrow band). If x is fp32[],
// low 16 bits are mantissa garbage (uniform exponent when viewed as bf16).
__global__ void k_detect(const unsigned int* __restrict__ xw, int* __restrict__ flag) {
    __shared__ int cnt;
    if (threadIdx.x == 0) cnt = 0;
    __syncthreads();
    unsigned int v = xw[threadIdx.x];
    int e = (v >> 7) & 0xFF;                      // bf16 exponent of low half
    int ok = (e >= 100 && e <= 133) ? 1 : 0;      // |v| roughly in [2^-27, 64]
    atomicAdd(&cnt, ok);
    __syncthreads();
    if (threadIdx.x == 0) *flag = (cnt >= 96) ? 1 : 0;
}

// ---------------- CSR build ----------------

__global__ void k_count(const int* __restrict__ dst, int* __restrict__ cnt) {
    int e = blockIdx.x * 256 + threadIdx.x;
    if (e < EE) atomicAdd(&cnt[dst[e]], 1);
}

__global__ __launch_bounds__(1024) void k_scan1(const int* __restrict__ cnt,
                                                int* __restrict__ rowptr,
                                                int* __restrict__ partials) {
    __shared__ int s[1024];
    int tid = threadIdx.x;
    int i = blockIdx.x * 1024 + tid;
    int v = (i < NN) ? cnt[i] : 0;
    s[tid] = v;
    __syncthreads();
    for (int off = 1; off < 1024; off <<= 1) {
        int t = (tid >= off) ? s[tid - off] : 0;
        __syncthreads();
        s[tid] += t;
        __syncthreads();
    }
    if (i < NN) rowptr[i + 1] = s[tid];
    if (tid == 1023) partials[blockIdx.x] = s[1023];
}

__global__ void k_scan2(int* __restrict__ partials, int nb) {
    if (threadIdx.x == 0 && blockIdx.x == 0) {
        int run = 0;
        for (int b = 0; b < nb; ++b) { int t = partials[b]; partials[b] = run; run += t; }
    }
}

__global__ void k_scan3(const int* __restrict__ cnt, int* __restrict__ rowptr,
                        const int* __restrict__ partials, int* __restrict__ cursor,
                        float* __restrict__ dis, float* __restrict__ dinv) {
    int i = blockIdx.x * 256 + threadIdx.x;
    if (i >= NN) return;
    int incl = rowptr[i + 1] + partials[i >> 10];
    rowptr[i + 1] = incl;
    cursor[i] = incl - cnt[i];
    if (i == 0) rowptr[0] = 0;
    float dg = (float)cnt[i] + 1.0f;
    dis[i] = rsqrtf(dg);
    dinv[i] = 1.0f / dg;
}

__global__ void k_fill(const int* __restrict__ src, const int* __restrict__ dst,
                       int* __restrict__ cursor, int* __restrict__ csr) {
    int e = blockIdx.x * 256 + threadIdx.x;
    if (e < EE) {
        int pos = atomicAdd(&cursor[dst[e]], 1);
        csr[pos] = src[e];
    }
}

// ---------------- dtype convert x -> fp32 ----------------

__global__ void k_cvt(const void* __restrict__ x, float* __restrict__ h,
                      const int* __restrict__ flag) {
    int bf = *flag;
    int i = blockIdx.x * 256 + threadIdx.x;
    if (i < NN * HH) h[i] = ldin(x, i, bf);
}

// ---------------- GEMM: Out[N,64] = A[N,64] @ W[64,64] ----------------

__global__ __launch_bounds__(256) void k_gemm(const float* __restrict__ A,
                                              const void* __restrict__ W,
                                              float* __restrict__ Out,
                                              const int* __restrict__ flag) {
    __shared__ float Wl[64 * 64];
    int bf = *flag;
    int tid = threadIdx.x;
    for (int idx = tid; idx < 4096; idx += 256)
        Wl[idx] = ldin(W, idx, bf);
    __syncthreads();
    int row = blockIdx.x * 64 + (tid >> 2);
    int c0 = (tid & 3) * 16;
    if (row >= NN) return;
    const float4* a4 = (const float4*)(A + (size_t)row * 64);
    const float4* w4 = (const float4*)Wl;
    float4 acc0 = {0,0,0,0}, acc1 = {0,0,0,0}, acc2 = {0,0,0,0}, acc3 = {0,0,0,0};
    #pragma unroll
    for (int kk = 0; kk < 16; ++kk) {
        float4 av = a4[kk];
        float as[4] = {av.x, av.y, av.z, av.w};
        #pragma unroll
        for (int j = 0; j < 4; ++j) {
            int k = kk * 4 + j;
            const float4* wr = w4 + ((k * 64 + c0) >> 2);
            float4 w0 = wr[0], w1 = wr[1], w2 = wr[2], w3 = wr[3];
            float a = as[j];
            acc0.x += a * w0.x; acc0.y += a * w0.y; acc0.z += a * w0.z; acc0.w += a * w0.w;
            acc1.x += a * w1.x; acc1.y += a * w1.y; acc1.z += a * w1.z; acc1.w += a * w1.w;
            acc2.x += a * w2.x; acc2.y += a * w2.y; acc2.z += a * w2.z; acc2.w += a * w2.w;
            acc3.x += a * w3.x; acc3.y += a * w3.y; acc3.z += a * w3.z; acc3.w += a * w3.w;
        }
    }
    float4* o4 = (float4*)(Out + (size_t)row * 64 + c0);
    o4[0] = acc0; o4[1] = acc1; o4[2] = acc2; o4[3] = acc3;
}

// ---------------- aggregate: one wave per node, lane = feature ----------------

__global__ __launch_bounds__(256) void k_agg(const float* __restrict__ xw,
                                             const int* __restrict__ rowptr,
                                             const int* __restrict__ csr,
                                             const float* __restrict__ dis,
                                             const float* __restrict__ dinv,
                                             const void* __restrict__ bias,
                                             float* __restrict__ out,
                                             const int* __restrict__ flag) {
    int bf = *flag;
    int wid = (blockIdx.x * 256 + threadIdx.x) >> 6;
    int f = threadIdx.x & 63;
    if (wid >= NN) return;
    int s = rowptr[wid], e = rowptr[wid + 1];
    float acc = 0.f;
    for (int i = s; i < e; ++i) {
        int sr = csr[i];
        acc += xw[(size_t)sr * 64 + f] * dis[sr];
    }
    out[(size_t)wid * 64 + f] = acc * dis[wid]
                              + xw[(size_t)wid * 64 + f] * dinv[wid]
                              + ldin(bias, f, bf);
}

// ---------------- BN stats in fp64 (col sums & sumsq) ----------------

__global__ __launch_bounds__(256) void k_stats(const float* __restrict__ h,
                                               double* __restrict__ stats) {
    __shared__ double psum[4][64], psq[4][64];
    int tid = threadIdx.x;
    int w = tid >> 6, col = tid & 63;
    double s = 0.0, q = 0.0;
    for (int r = blockIdx.x * 4 + w; r < NN; r += gridDim.x * 4) {
        double v = (double)h[(size_t)r * 64 + col];
        s += v; q += v * v;
    }
    psum[w][col] = s; psq[w][col] = q;
    __syncthreads();
    if (w == 0) {
        double ts = psum[0][col] + psum[1][col] + psum[2][col] + psum[3][col];
        double tq = psq[0][col] + psq[1][col] + psq[2][col] + psq[3][col];
        atomicAdd(&stats[col], ts);
        atomicAdd(&stats[64 + col], tq);
    }
}

__global__ void k_bnrelu(float* __restrict__ h, const double* __restrict__ stats,
                         const void* __restrict__ g, const void* __restrict__ be,
                         const int* __restrict__ flag) {
    int bf = *flag;
    int i = blockIdx.x * 256 + threadIdx.x;
    if (i >= NN * HH) return;
    int col = i & 63;
    double m = stats[col] * (1.0 / NN);
    double v = stats[64 + col] * (1.0 / NN) - m * m;
    float inv = (float)(1.0 / sqrt(v + 1e-5));
    float val = ((float)(h[i] - m)) * inv * ldin(g, col, bf) + ldin(be, col, bf);
    h[i] = fmaxf(val, 0.f);
}

// ---------------- pooling + head ----------------

__global__ void k_pool(const float* __restrict__ h, const int* __restrict__ batch,
                       float* __restrict__ pooled, float* __restrict__ gcnt) {
    int i = blockIdx.x * 256 + threadIdx.x;
    if (i >= NN * HH) return;
    int node = i >> 6, f = i & 63;
    int gi = batch[node];
    atomicAdd(&pooled[gi * 64 + f], h[i]);
    if (f == 0) atomicAdd(&gcnt[gi], 1.0f);
}

__global__ __launch_bounds__(64) void k_head(const float* __restrict__ pooled,
                                             const float* __restrict__ gcnt,
                                             const void* __restrict__ fc1w,
                                             const void* __restrict__ fc1b,
                                             const void* __restrict__ fc2w,
                                             const void* __restrict__ fc2b,
                                             void* __restrict__ out,
                                             const int* __restrict__ flag) {
    __shared__ float sp[64], sz[32], so[10];
    __shared__ float slse;
    int bf = *flag;
    int g = blockIdx.x, t = threadIdx.x;
    float cv = fmaxf(gcnt[g], 1.0f);
    sp[t] = pooled[g * 64 + t] / cv;
    __syncthreads();
    if (t < 32) {
        float acc = ldin(fc1b, t, bf);
        for (int k = 0; k < 64; ++k) acc += sp[k] * ldin(fc1w, k * 32 + t, bf);
        sz[t] = fmaxf(acc, 0.f);
    }
    __syncthreads();
    if (t < 10) {
        float acc = ldin(fc2b, t, bf);
        for (int k = 0; k < 32; ++k) acc += sz[k] * ldin(fc2w, k * 10 + t, bf);
        so[t] = acc;
    }
    __syncthreads();
    if (t == 0) {
        float m = so[0];
        for (int c = 1; c < 10; ++c) m = fmaxf(m, so[c]);
        float s = 0.f;
        for (int c = 0; c < 10; ++c) s += expf(so[c] - m);
        slse = m + logf(s);
    }
    __syncthreads();
    if (t < 10) stout(out, g * 10 + t, so[t] - slse, bf);
}

// ---------------- launch ----------------

extern "C" void kernel_launch(void* const* d_in, const int* in_sizes, int n_in,
                              void* d_out, int out_size, void* d_ws, size_t ws_size,
                              hipStream_t stream) {
    const void* x     = d_in[0];
    const int*  ei    = (const int*)d_in[1];
    const int*  batch = (const int*)d_in[2];
    const int* srcp = ei;
    const int* dstp = ei + EE;
    const void* W[3]  = {d_in[3],  d_in[7],  d_in[11]};
    const void* bb[3] = {d_in[4],  d_in[8],  d_in[12]};
    const void* gg[3] = {d_in[5],  d_in[9],  d_in[13]};
    const void* be[3] = {d_in[6],  d_in[10], d_in[14]};
    const void* fc1w = d_in[15];
    const void* fc1b = d_in[16];
    const void* fc2w = d_in[17];
    const void* fc2b = d_in[18];

    char* ws = (char*)d_ws;
    size_t off = 0;
    auto alloc = [&](size_t bytes) { size_t o = off; off = (off + bytes + 255) & ~(size_t)255; return o; };
    float*  hcur   = (float*) (ws + alloc((size_t)NN * HH * 4));
    float*  xw     = (float*) (ws + alloc((size_t)NN * HH * 4));
    int*    cnt    = (int*)   (ws + alloc((size_t)NN * 4));
    int*    rowptr = (int*)   (ws + alloc((size_t)(NN + 1) * 4));
    int*    cursor = (int*)   (ws + alloc((size_t)NN * 4));
    int*    csr    = (int*)   (ws + alloc((size_t)EE * 4));
    float*  dis    = (float*) (ws + alloc((size_t)NN * 4));
    float*  dinv   = (float*) (ws + alloc((size_t)NN * 4));
    double* stats  = (double*)(ws + alloc(128 * 8));
    int*    parts  = (int*)   (ws + alloc(256 * 4));
    float*  pooled = (float*) (ws + alloc((size_t)GG * HH * 4));
    float*  gcnt   = (float*) (ws + alloc((size_t)GG * 4));
    int*    dflag  = (int*)   (ws + alloc(256));
    if (off > ws_size) return;

    const int NB = (NN + 1023) / 1024;

    k_detect<<<1, 128, 0, stream>>>((const unsigned int*)x, dflag);
    hipMemsetAsync(cnt, 0, (size_t)NN * 4, stream);
    k_count<<<(EE + 255) / 256, 256, 0, stream>>>(dstp, cnt);
    k_scan1<<<NB, 1024, 0, stream>>>(cnt, rowptr, parts);
    k_scan2<<<1, 64, 0, stream>>>(parts, NB);
    k_scan3<<<(NN + 255) / 256, 256, 0, stream>>>(cnt, rowptr, parts, cursor, dis, dinv);
    k_fill<<<(EE + 255) / 256, 256, 0, stream>>>(srcp, dstp, cursor, csr);
    k_cvt<<<(NN * HH + 255) / 256, 256, 0, stream>>>(x, hcur, dflag);

    for (int l = 0; l < 3; ++l) {
        k_gemm<<<(NN + 63) / 64, 256, 0, stream>>>(hcur, W[l], xw, dflag);
        k_agg<<<(NN * 64 + 255) / 256, 256, 0, stream>>>(xw, rowptr, csr, dis, dinv, bb[l], hcur, dflag);
        hipMemsetAsync(stats, 0, 128 * 8, stream);
        k_stats<<<512, 256, 0, stream>>>(hcur, stats);
        k_bnrelu<<<(NN * HH + 255) / 256, 256, 0, stream>>>(hcur, stats, gg[l], be[l], dflag);
    }

    hipMemsetAsync(pooled, 0, (size_t)GG * HH * 4, stream);
    hipMemsetAsync(gcnt, 0, (size_t)GG * 4, stream);
    k_pool<<<(NN * HH + 255) / 256, 256, 0, stream>>>(hcur, batch, pooled, gcnt);
    k_head<<<GG, 64, 0, stream>>>(pooled, gcnt, fc1w, fc1b, fc2w, fc2b, d_out, dflag);
}

// Round 3
// 569.857 us; speedup vs baseline: 1.6501x; 1.6501x over previous
//
#include <hip/hip_runtime.h>
#include <hip/hip_bf16.h>

#define NN 100000
#define EE 1200000
#define HH 64
#define CC 10
#define GG 1000

typedef unsigned int uint;
typedef unsigned short ushort;

// ---------- helpers ----------

__device__ __forceinline__ float b2fu(ushort u) {
    uint w = ((uint)u) << 16;
    float f; __builtin_memcpy(&f, &w, 4); return f;
}

__device__ __forceinline__ uint fbits(float f) {
    uint w; __builtin_memcpy(&w, &f, 4); return w;
}

__device__ __forceinline__ float bitsf(uint w) {
    float f; __builtin_memcpy(&f, &w, 4); return f;
}

__device__ __forceinline__ ushort f2b(float f) {
    uint w = fbits(f);
    w += 0x7FFFu + ((w >> 16) & 1u);   // rne
    return (ushort)(w >> 16);
}

__device__ __forceinline__ uint f2b2(float lo, float hi) {
    uint a = fbits(lo), b = fbits(hi);
    a += 0x7FFFu + ((a >> 16) & 1u);
    b += 0x7FFFu + ((b >> 16) & 1u);
    return (a >> 16) | (b & 0xFFFF0000u);
}

// dtype-flexible input load (bf=1: bf16, bf=0: fp32)
__device__ __forceinline__ float ldin(const void* p, int i, int bf) {
    if (bf) return b2fu(((const ushort*)p)[i]);
    return ((const float*)p)[i];
}

__device__ __forceinline__ void stout(void* p, int i, float v, int bf) {
    if (bf) ((ushort*)p)[i] = f2b(v);
    else    ((float*)p)[i] = v;
}

__global__ void k_detect(const uint* __restrict__ xw, int* __restrict__ flag) {
    __shared__ int cnt;
    if (threadIdx.x == 0) cnt = 0;
    __syncthreads();
    uint v = xw[threadIdx.x];
    int e = (v >> 7) & 0xFF;
    int ok = (e >= 100 && e <= 133) ? 1 : 0;
    atomicAdd(&cnt, ok);
    __syncthreads();
    if (threadIdx.x == 0) *flag = (cnt >= 96) ? 1 : 0;
}

// ---------------- CSR build ----------------

__global__ void k_count(const int* __restrict__ dst, int* __restrict__ cnt) {
    int e = blockIdx.x * 256 + threadIdx.x;
    if (e < EE) atomicAdd(&cnt[dst[e]], 1);
}

__global__ __launch_bounds__(1024) void k_scan1(const int* __restrict__ cnt,
                                                int* __restrict__ rowptr,
                                                int* __restrict__ partials) {
    __shared__ int s[1024];
    int tid = threadIdx.x;
    int i = blockIdx.x * 1024 + tid;
    int v = (i < NN) ? cnt[i] : 0;
    s[tid] = v;
    __syncthreads();
    for (int off = 1; off < 1024; off <<= 1) {
        int t = (tid >= off) ? s[tid - off] : 0;
        __syncthreads();
        s[tid] += t;
        __syncthreads();
    }
    if (i < NN) rowptr[i + 1] = s[tid];
    if (tid == 1023) partials[blockIdx.x] = s[1023];
}

__global__ void k_scan2(int* __restrict__ partials, int nb) {
    if (threadIdx.x == 0 && blockIdx.x == 0) {
        int run = 0;
        for (int b = 0; b < nb; ++b) { int t = partials[b]; partials[b] = run; run += t; }
    }
}

__global__ void k_scan3(const int* __restrict__ cnt, int* __restrict__ rowptr,
                        const int* __restrict__ partials, int* __restrict__ cursor,
                        float* __restrict__ dis) {
    int i = blockIdx.x * 256 + threadIdx.x;
    if (i >= NN) return;
    int incl = rowptr[i + 1] + partials[i >> 10];
    rowptr[i + 1] = incl;
    cursor[i] = incl - cnt[i];
    if (i == 0) rowptr[0] = 0;
    dis[i] = rsqrtf((float)cnt[i] + 1.0f);
}

__global__ void k_fill(const int* __restrict__ src, const int* __restrict__ dst,
                       int* __restrict__ cursor, int* __restrict__ csr) {
    int e = blockIdx.x * 256 + threadIdx.x;
    if (e < EE) {
        int pos = atomicAdd(&cursor[dst[e]], 1);
        csr[pos] = src[e];
    }
}

// ------- GEMM: xws[N,64](bf16) = BNReLU?(A)[N,64] @ W[64,64], scaled by dis[row] -------
// MODE 0: A = raw input x (dtype via flag), no BN.
// MODE 1: A = hagg (bf16) with BN(stats,g,be)+ReLU applied during staging.

template<int MODE>
__global__ __launch_bounds__(256) void k_gemm(const void* __restrict__ A,
                                              const void* __restrict__ Wp,
                                              const float* __restrict__ stats,
                                              const void* __restrict__ gam,
                                              const void* __restrict__ bet,
                                              const float* __restrict__ dis,
                                              ushort* __restrict__ outb,
                                              const int* __restrict__ flag) {
    __shared__ float Wl[64 * 64];
    __shared__ float Al[64 * 68];   // +4 pad: 2-way banks only (free)
    __shared__ float sc[64], sh[64];
    int bf = *flag;
    int tid = threadIdx.x;
    int row0 = blockIdx.x * 64;

    if (MODE == 1 && tid < 64) {
        float m = stats[tid] * (1.0f / NN);
        float v = stats[64 + tid] * (1.0f / NN) - m * m;
        float s = rsqrtf(v + 1e-5f) * ldin(gam, tid, bf);
        sc[tid] = s;
        sh[tid] = ldin(bet, tid, bf) - m * s;
    }
    // W staging
    if (bf) {
        for (int i = tid; i < 4096; i += 256) Wl[i] = ldin(Wp, i, 1);
    } else {
        const float4* w4 = (const float4*)Wp;
        float4* wl4 = (float4*)Wl;
        for (int i = tid; i < 1024; i += 256) wl4[i] = w4[i];
    }
    __syncthreads();

    // A staging: 64 rows x 64 cols; thread -> row ra=tid>>2, cols ca..ca+15
    {
        int ra = tid >> 2, ca = (tid & 3) * 16;
        int grow = row0 + ra;
        float* dstl = &Al[ra * 68 + ca];
        if (grow < NN) {
            if (MODE == 0) {
                if (bf) {
                    const ushort* xp = (const ushort*)A + (size_t)grow * 64 + ca;
                    for (int c = 0; c < 16; ++c) dstl[c] = b2fu(xp[c]);
                } else {
                    const float4* ap = (const float4*)((const float*)A + (size_t)grow * 64 + ca);
                    for (int c = 0; c < 4; ++c) {
                        float4 v = ap[c];
                        dstl[c*4+0] = v.x; dstl[c*4+1] = v.y; dstl[c*4+2] = v.z; dstl[c*4+3] = v.w;
                    }
                }
            } else {
                const uint* hp = (const uint*)A + ((size_t)grow * 64 + ca) / 2;
                for (int cc = 0; cc < 8; ++cc) {
                    uint u = hp[cc];
                    float a = bitsf(u << 16);
                    float b = bitsf(u & 0xFFFF0000u);
                    int c = ca + cc * 2;
                    dstl[cc*2+0] = fmaxf(fmaf(a, sc[c],   sh[c]),   0.f);
                    dstl[cc*2+1] = fmaxf(fmaf(b, sc[c+1], sh[c+1]), 0.f);
                }
            }
        } else {
            for (int c = 0; c < 16; ++c) dstl[c] = 0.f;
        }
    }
    __syncthreads();

    int ra = tid >> 2, c0 = (tid & 3) * 16;
    int grow = row0 + ra;
    const float4* w4 = (const float4*)Wl;
    float4 acc0 = {0,0,0,0}, acc1 = {0,0,0,0}, acc2 = {0,0,0,0}, acc3 = {0,0,0,0};
    #pragma unroll
    for (int kk = 0; kk < 16; ++kk) {
        float4 av = *(const float4*)&Al[ra * 68 + kk * 4];
        float as[4] = {av.x, av.y, av.z, av.w};
        #pragma unroll
        for (int j = 0; j < 4; ++j) {
            int k = kk * 4 + j;
            const float4* wr = w4 + ((k * 64 + c0) >> 2);
            float4 w0 = wr[0], w1 = wr[1], w2 = wr[2], w3 = wr[3];
            float a = as[j];
            acc0.x += a*w0.x; acc0.y += a*w0.y; acc0.z += a*w0.z; acc0.w += a*w0.w;
            acc1.x += a*w1.x; acc1.y += a*w1.y; acc1.z += a*w1.z; acc1.w += a*w1.w;
            acc2.x += a*w2.x; acc2.y += a*w2.y; acc2.z += a*w2.z; acc2.w += a*w2.w;
            acc3.x += a*w3.x; acc3.y += a*w3.y; acc3.z += a*w3.z; acc3.w += a*w3.w;
        }
    }
    if (grow >= NN) return;
    float d = dis[grow];
    uint4 p0, p1;
    p0.x = f2b2(acc0.x*d, acc0.y*d); p0.y = f2b2(acc0.z*d, acc0.w*d);
    p0.z = f2b2(acc1.x*d, acc1.y*d); p0.w = f2b2(acc1.z*d, acc1.w*d);
    p1.x = f2b2(acc2.x*d, acc2.y*d); p1.y = f2b2(acc2.z*d, acc2.w*d);
    p1.z = f2b2(acc3.x*d, acc3.y*d); p1.w = f2b2(acc3.z*d, acc3.w*d);
    uint4* op = (uint4*)(outb + (size_t)grow * 64 + c0);
    op[0] = p0; op[1] = p1;
}

// ------- aggregate: hagg[dst] = bf16( dis[dst] * (xws[dst] + sum xws[src]) ) -------

__global__ __launch_bounds__(256) void k_agg(const ushort* __restrict__ xws,
                                             const int* __restrict__ rowptr,
                                             const int* __restrict__ csr,
                                             const float* __restrict__ dis,
                                             ushort* __restrict__ hagg) {
    int wid = (blockIdx.x * 256 + threadIdx.x) >> 6;
    int f = threadIdx.x & 63;
    if (wid >= NN) return;
    int s = rowptr[wid], e = rowptr[wid + 1];
    float acc0 = b2fu(xws[(size_t)wid * 64 + f]);   // self term
    float acc1 = 0.f;
    int i = s;
    while (i < e) {
        int m = e - i; if (m > 64) m = 64;
        int idx = (f < m) ? csr[i + f] : 0;
        int j = 0;
        for (; j + 4 <= m; j += 4) {
            int s0 = __shfl(idx, j), s1 = __shfl(idx, j + 1);
            int s2 = __shfl(idx, j + 2), s3 = __shfl(idx, j + 3);
            float v0 = b2fu(xws[(size_t)s0 * 64 + f]);
            float v1 = b2fu(xws[(size_t)s1 * 64 + f]);
            float v2 = b2fu(xws[(size_t)s2 * 64 + f]);
            float v3 = b2fu(xws[(size_t)s3 * 64 + f]);
            acc0 += v0 + v2;
            acc1 += v1 + v3;
        }
        for (; j < m; ++j)
            acc1 += b2fu(xws[(size_t)__shfl(idx, j) * 64 + f]);
        i += m;
    }
    hagg[(size_t)wid * 64 + f] = f2b((acc0 + acc1) * dis[wid]);
}

// ------- BN stats on bf16 hagg: stats[0:64]=col sums, [64:128]=col sumsq -------

__global__ __launch_bounds__(256) void k_stats(const uint* __restrict__ h2,
                                               float* __restrict__ stats) {
    __shared__ float ls[2][64];
    int tid = threadIdx.x;
    int p = tid & 31, grp = tid >> 5;   // col pair p -> cols 2p,2p+1
    float s0 = 0, q0 = 0, s1 = 0, q1 = 0;
    for (int r = blockIdx.x * 8 + grp; r < NN; r += gridDim.x * 8) {
        uint u = h2[(size_t)r * 32 + p];
        float a = bitsf(u << 16);
        float b = bitsf(u & 0xFFFF0000u);
        s0 += a; q0 += a * a;
        s1 += b; q1 += b * b;
    }
    if (tid < 64) { ls[0][tid] = 0.f; ls[1][tid] = 0.f; }
    __syncthreads();
    atomicAdd(&ls[0][2*p],   s0);
    atomicAdd(&ls[0][2*p+1], s1);
    atomicAdd(&ls[1][2*p],   q0);
    atomicAdd(&ls[1][2*p+1], q1);
    __syncthreads();
    if (tid < 64) {
        atomicAdd(&stats[tid],      ls[0][tid]);
        atomicAdd(&stats[64 + tid], ls[1][tid]);
    }
}

// ------- graph boundaries from sorted batch -------

__global__ void k_bounds(const int* __restrict__ batch, int* __restrict__ gstart) {
    int i = blockIdx.x * 256 + threadIdx.x;
    if (i > NN) return;
    int b  = (i < NN) ? batch[i] : GG;
    int pb = (i == 0) ? -1 : batch[i - 1];
    for (int g = pb + 1; g <= b; ++g) gstart[g] = i;
}

// ------- fused BN+ReLU + mean-pool + MLP head + log_softmax, one block per graph -------

__global__ __launch_bounds__(256) void k_poolhead(const ushort* __restrict__ hagg,
                                                  const float* __restrict__ stats,
                                                  const void* __restrict__ gam,
                                                  const void* __restrict__ bet,
                                                  const int* __restrict__ gstart,
                                                  const void* __restrict__ fc1w,
                                                  const void* __restrict__ fc1b,
                                                  const void* __restrict__ fc2w,
                                                  const void* __restrict__ fc2b,
                                                  void* __restrict__ out,
                                                  const int* __restrict__ flag) {
    __shared__ float part[4][64];
    __shared__ float pooled[64], z1[32], z2[10], slse;
    int bf = *flag;
    int g = blockIdx.x, tid = threadIdx.x;
    int w = tid >> 6, f = tid & 63;
    int s = gstart[g], e = gstart[g + 1];
    float m = stats[f] * (1.0f / NN);
    float v = stats[64 + f] * (1.0f / NN) - m * m;
    float sc = rsqrtf(v + 1e-5f) * ldin(gam, f, bf);
    float sh = ldin(bet, f, bf) - m * sc;
    float acc = 0.f;
    for (int r = s + w; r < e; r += 4)
        acc += fmaxf(fmaf(b2fu(hagg[(size_t)r * 64 + f]), sc, sh), 0.f);
    part[w][f] = acc;
    __syncthreads();
    if (w == 0)
        pooled[f] = (part[0][f] + part[1][f] + part[2][f] + part[3][f])
                  / fmaxf((float)(e - s), 1.0f);
    __syncthreads();
    if (tid < 32) {
        float a = ldin(fc1b, tid, bf);
        for (int k = 0; k < 64; ++k) a += pooled[k] * ldin(fc1w, k * 32 + tid, bf);
        z1[tid] = fmaxf(a, 0.f);
    }
    __syncthreads();
    if (tid < 10) {
        float a = ldin(fc2b, tid, bf);
        for (int k = 0; k < 32; ++k) a += z1[k] * ldin(fc2w, k * 10 + tid, bf);
        z2[tid] = a;
    }
    __syncthreads();
    if (tid == 0) {
        float mm = z2[0];
        for (int c = 1; c < 10; ++c) mm = fmaxf(mm, z2[c]);
        float ss = 0.f;
        for (int c = 0; c < 10; ++c) ss += expf(z2[c] - mm);
        slse = mm + logf(ss);
    }
    __syncthreads();
    if (tid < 10) stout(out, g * 10 + tid, z2[tid] - slse, bf);
}

// ---------------- launch ----------------

extern "C" void kernel_launch(void* const* d_in, const int* in_sizes, int n_in,
                              void* d_out, int out_size, void* d_ws, size_t ws_size,
                              hipStream_t stream) {
    const void* x     = d_in[0];
    const int*  ei    = (const int*)d_in[1];
    const int*  batch = (const int*)d_in[2];
    const int* srcp = ei;
    const int* dstp = ei + EE;
    const void* W[3]  = {d_in[3],  d_in[7],  d_in[11]};
    const void* gg_[3] = {d_in[5],  d_in[9],  d_in[13]};
    const void* be_[3] = {d_in[6],  d_in[10], d_in[14]};
    const void* fc1w = d_in[15];
    const void* fc1b = d_in[16];
    const void* fc2w = d_in[17];
    const void* fc2b = d_in[18];

    char* ws = (char*)d_ws;
    size_t off = 0;
    auto alloc = [&](size_t bytes) { size_t o = off; off = (off + bytes + 255) & ~(size_t)255; return o; };
    ushort* xws    = (ushort*)(ws + alloc((size_t)NN * HH * 2));
    ushort* hagg   = (ushort*)(ws + alloc((size_t)NN * HH * 2));
    int*    cnt    = (int*)   (ws + alloc((size_t)NN * 4));
    int*    rowptr = (int*)   (ws + alloc((size_t)(NN + 1) * 4));
    int*    cursor = (int*)   (ws + alloc((size_t)NN * 4));
    int*    csr    = (int*)   (ws + alloc((size_t)EE * 4));
    float*  dis    = (float*) (ws + alloc((size_t)NN * 4));
    float*  stats  = (float*) (ws + alloc(128 * 4));
    int*    parts  = (int*)   (ws + alloc(256 * 4));
    int*    gstart = (int*)   (ws + alloc((size_t)(GG + 1) * 4));
    int*    dflag  = (int*)   (ws + alloc(256));
    if (off > ws_size) return;

    const int NB = (NN + 1023) / 1024;

    k_detect<<<1, 128, 0, stream>>>((const uint*)x, dflag);
    hipMemsetAsync(cnt, 0, (size_t)NN * 4, stream);
    k_count<<<(EE + 255) / 256, 256, 0, stream>>>(dstp, cnt);
    k_scan1<<<NB, 1024, 0, stream>>>(cnt, rowptr, parts);
    k_scan2<<<1, 64, 0, stream>>>(parts, NB);
    k_scan3<<<(NN + 255) / 256, 256, 0, stream>>>(cnt, rowptr, parts, cursor, dis);
    k_fill<<<(EE + 255) / 256, 256, 0, stream>>>(srcp, dstp, cursor, csr);
    k_bounds<<<(NN + 256) / 256, 256, 0, stream>>>(batch, gstart);

    const int GB = (NN + 63) / 64;

    // layer 0
    k_gemm<0><<<GB, 256, 0, stream>>>(x, W[0], stats, nullptr, nullptr, dis, xws, dflag);
    k_agg<<<(NN * 64 + 255) / 256, 256, 0, stream>>>(xws, rowptr, csr, dis, hagg);
    hipMemsetAsync(stats, 0, 128 * 4, stream);
    k_stats<<<256, 256, 0, stream>>>((const uint*)hagg, stats);
    // layer 1
    k_gemm<1><<<GB, 256, 0, stream>>>(hagg, W[1], stats, gg_[0], be_[0], dis, xws, dflag);
    k_agg<<<(NN * 64 + 255) / 256, 256, 0, stream>>>(xws, rowptr, csr, dis, hagg);
    hipMemsetAsync(stats, 0, 128 * 4, stream);
    k_stats<<<256, 256, 0, stream>>>((const uint*)hagg, stats);
    // layer 2
    k_gemm<1><<<GB, 256, 0, stream>>>(hagg, W[2], stats, gg_[1], be_[1], dis, xws, dflag);
    k_agg<<<(NN * 64 + 255) / 256, 256, 0, stream>>>(xws, rowptr, csr, dis, hagg);
    hipMemsetAsync(stats, 0, 128 * 4, stream);
    k_stats<<<256, 256, 0, stream>>>((const uint*)hagg, stats);
    // head
    k_poolhead<<<GG, 256, 0, stream>>>(hagg, stats, gg_[2], be_[2], gstart,
                                       fc1w, fc1b, fc2w, fc2b, d_out, dflag);
}